// Round 9
// baseline (713.053 us; speedup 1.0000x reference)
//
#include <hip/hip_runtime.h>
#include <math.h>

// Grid constants from the reference
#define GH 512
#define GW 512
#define GHW (GH * GW)
#define RR 3
#define SH 32            // strip height
#define SSHIFT 5
#define NSTRIP (GH / SH) // 16
#define CAP 1536         // per-strip bin capacity (mean ~625, max ~750 @ B=8)
#define THR 1024
// Barrier magics: poll for exact membership (poison-safe, monotone phases).
#define MAGIC1 0x4D414701
#define MAGIC2 0x4D414702
#define MAGIC3 0x4D414703

typedef float f32x4 __attribute__((ext_vector_type(4)));  // nontemporal builtins
// reject HIP_vector_type (R7 compile fail) - use clang ext_vector_type.

// Precision model (validated, absmax 3.9e-3): pure f32 chain, *10.0f voxel
// scale, f32 expf, f32 pose (bit-identical to f64 for identity-rotation
// poses; validated end-to-end R8). Heat max is order-free (int-bit atomicMax
// on positive floats) => binning/strip order cannot perturb results.
//
// Cost model (fitted R0-R8): T = 21 fixed + 41 ws-fill + Sum(device) + 13/dispatch.
// Ledger: coop launch +35us (R2,R4 - never). Gather ~28us at ANY occupancy/
// vectorization (R6,R8) => TCP-transaction-bound (strided pt lines + 1 random
// heat line per pt). Heat scan cost tracks total re-read work: SH16/4.2M=45us
// (R3), SH32/2.1M=26us (R6) => kill the redundant scan via binning (R0's
// scatter was ~5us). R9: ONE dispatch, software barrier (all 256 blocks
// resident by construction: 256 blocks x 1024thr on 256 CUs, 72KB LDS).

__device__ __forceinline__ void compute_pose(const float* __restrict__ P0,
                                             const float* __restrict__ P1,
                                             float* __restrict__ T) {
    float a00 = P1[0], a01 = P1[1], a02 = P1[2],  t1x = P1[3];
    float a10 = P1[4], a11 = P1[5], a12 = P1[6],  t1y = P1[7];
    float a20 = P1[8], a21 = P1[9], a22 = P1[10], t1z = P1[11];
    float c00 = a11 * a22 - a12 * a21;
    float c01 = a12 * a20 - a10 * a22;
    float c02 = a10 * a21 - a11 * a20;
    float det = a00 * c00 + a01 * c01 + a02 * c02;
    float id = 1.0f / det;
    float r00 = c00 * id;
    float r01 = (a02 * a21 - a01 * a22) * id;
    float r02 = (a01 * a12 - a02 * a11) * id;
    float r10 = c01 * id;
    float r11 = (a00 * a22 - a02 * a20) * id;
    float r12 = (a02 * a10 - a00 * a12) * id;
    float r20 = c02 * id;
    float r21 = (a01 * a20 - a00 * a21) * id;
    float r22 = (a00 * a11 - a01 * a10) * id;

    float b00 = P0[0], b01 = P0[1], b02 = P0[2],  t0x = P0[3];
    float b10 = P0[4], b11 = P0[5], b12 = P0[6],  t0y = P0[7];
    float b20 = P0[8], b21 = P0[9], b22 = P0[10], t0z = P0[11];
    float dx = t0x - t1x, dy = t0y - t1y, dz = t0z - t1z;

    T[0]  = r00 * b00 + r01 * b10 + r02 * b20;
    T[1]  = r00 * b01 + r01 * b11 + r02 * b21;
    T[2]  = r00 * b02 + r01 * b12 + r02 * b22;
    T[3]  = r00 * dx + r01 * dy + r02 * dz;
    T[4]  = r10 * b00 + r11 * b10 + r12 * b20;
    T[5]  = r10 * b01 + r11 * b11 + r12 * b21;
    T[6]  = r10 * b02 + r11 * b12 + r12 * b22;
    T[7]  = r10 * dx + r11 * dy + r12 * dz;
    T[8]  = r20 * b00 + r21 * b10 + r22 * b20;
    T[9]  = r20 * b01 + r21 * b11 + r22 * b21;
    T[10] = r20 * b02 + r21 * b12 + r22 * b22;
    T[11] = r20 * dx + r21 * dy + r22 * dz;
}

__device__ __forceinline__ void voxelize_xyz(float x, float y, float z,
                                             const float* __restrict__ T, // or nullptr
                                             float& px, float& py,
                                             int& ix, int& iy, bool& valid) {
    if (T) {
        float nx = T[0] * x + T[1] * y + T[2] * z + T[3];
        float ny = T[4] * x + T[5] * y + T[6] * z + T[7];
        float nz = T[8] * x + T[9] * y + T[10] * z + T[11];
        x = nx; y = ny; z = nz;
    }
    px = (x - 0.0f) * 10.0f;
    py = (y - (-25.6f)) * 10.0f;
    ix = (int)floorf(px);
    iy = (int)floorf(py);
    valid = (ix >= 0) & (ix < GH) & (iy >= 0) & (iy < GW) &
            (z >= -3.0f) & (z < 3.0f);
}

// All-resident software grid barrier. Writer: release-store MAGIC (flushes
// this block's prior stores to device coherence point). Poller: relaxed
// agent-scope atomic loads (bypass stale L2), exact-match against the valid
// magic set (monotone phases => no ABA deadlock; poison != magics w.h.p.).
// Post-poll full fence invalidates L1/L2 before any post-barrier load.
__device__ __forceinline__ void gbar(int* slots, int nblk, int blk, int tid,
                                     int magic, bool later_ok2, bool later_ok3) {
    __threadfence();
    __syncthreads();
    if (tid == 0)
        __hip_atomic_store(&slots[blk], magic, __ATOMIC_RELEASE,
                           __HIP_MEMORY_SCOPE_AGENT);
    if (tid < nblk) {
        for (;;) {
            int v = __hip_atomic_load(&slots[tid], __ATOMIC_RELAXED,
                                      __HIP_MEMORY_SCOPE_AGENT);
            if (v == magic || (later_ok2 && v == MAGIC2) ||
                (later_ok3 && v == MAGIC3)) break;
            __builtin_amdgcn_s_sleep(2);
        }
    }
    __syncthreads();
    __threadfence();
}

// Phases (gated by [phase_lo, phase_hi], barriers only when do_bar):
//  0: pose->LDS, zero own bin count          | bar M1
//  1: scatter radar pts -> strip bins (px,py)| bar M2
//  2: per-strip splat from own bin -> heat   | bar M3
//  3: fused gather -> out
// blk decode (phases 2): b=blk%B, map=(blk/B)&1, sx=blk/(2B); bin==blk.
__global__ __launch_bounds__(THR)
void mega_kernel(const float* __restrict__ pc0,
                 const float* __restrict__ pc1,
                 const float* __restrict__ radar0,
                 const float* __restrict__ radar1,
                 const float* __restrict__ pose0,
                 const float* __restrict__ pose1,
                 float* __restrict__ heat0,
                 float* __restrict__ heat1,
                 float2* __restrict__ entries,
                 int* __restrict__ counts,
                 int* __restrict__ slots,
                 float* __restrict__ out,
                 int B, int N, int M,
                 int phase_lo, int phase_hi, int do_bar, int vec_ok) {
    __shared__ int strip[SH * GW];   // 64 KB
    __shared__ float2 sp[CAP];       // 12 KB
    __shared__ float Tsh[8][12];

    const int tid = threadIdx.x;
    const int blk = blockIdx.x;
    const int nblk = gridDim.x;
    const int BM = B * M;

    if (tid < B) compute_pose(pose0 + tid * 16, pose1 + tid * 16, &Tsh[tid][0]);

    // ---- Phase 0: zero own bin count ----
    if (phase_lo <= 0) {
        if (tid == 0) counts[blk] = 0;
    }
    __syncthreads();   // Tsh ready for all
    if (phase_lo <= 0 && phase_hi >= 1 && do_bar)
        gbar(slots, nblk, blk, tid, MAGIC1, true, true);
    if (phase_hi < 1) return;

    // ---- Phase 1: scatter (each point -> 1-2 strip bins, store (px,py)) ----
    if (phase_lo <= 1) {
        for (int t = blk * THR + tid; t < 2 * BM; t += nblk * THR) {
            int map = t / BM;
            int rem = t - map * BM;
            int b = rem / M;
            const float* radar = map ? radar1 : radar0;
            const float* p = radar + (size_t)rem * 6;
            float px, py; int ix, iy; bool valid;
            voxelize_xyz(p[0], p[1], p[2], map ? nullptr : &Tsh[b][0],
                         px, py, ix, iy, valid);
            if (!valid) continue;
            int sxlo = max(ix - RR, 0) >> SSHIFT;
            int sxhi = min(ix + RR, GH - 1) >> SSHIFT;
            for (int sx = sxlo; sx <= sxhi; sx++) {
                int bin = sx * (2 * B) + map * B + b;
                int slot = atomicAdd(&counts[bin], 1);
                if (slot < CAP)
                    entries[(size_t)bin * CAP + slot] = make_float2(px, py);
            }
        }
    }
    // zero strip LDS while scatter traffic drains (block-local, pre-splat)
    {
        const int4 z4 = make_int4(0, 0, 0, 0);
        for (int c4 = tid * 4; c4 < SH * GW; c4 += 4 * THR)
            *reinterpret_cast<int4*>(&strip[c4]) = z4;
    }
    if (phase_lo <= 1 && phase_hi >= 2 && do_bar)
        gbar(slots, nblk, blk, tid, MAGIC2, false, true);
    if (phase_hi < 2) return;

    // ---- Phase 2: per-strip splat from own bin ----
    if (phase_lo <= 2) {
        const int b = blk % B;
        const int map = (blk / B) & 1;
        const int sx = blk / (2 * B);
        const int x0 = sx << SSHIFT;

        int n = counts[blk];
        if (n > CAP) n = CAP;
        for (int i = tid; i < n; i += THR) sp[i] = entries[(size_t)blk * CAP + i];
        __syncthreads();

        const int total = n * 49;
        for (int t = tid; t < total; t += THR) {
            int pi = t / 49;
            int c = t - pi * 49;
            float px = sp[pi].x;
            float py = sp[pi].y;
            int ix = (int)floorf(px);
            int iy = (int)floorf(py);
            int dx = c / 7 - RR;
            int dy = c - (c / 7) * 7 - RR;
            int gx = ix + dx, gy = iy + dy;
            if (gx < x0 || gx >= x0 + SH || gy < 0 || gy >= GW) continue;
            float ddx = ((float)gx + 0.5f) - px;
            float ddy = ((float)gy + 0.5f) - py;
            float d2 = ddx * ddx + ddy * ddy;
            float val = expf(-d2 / 4.5f);
            atomicMax(&strip[(gx - x0) * GW + gy], __float_as_int(val));
        }
        __syncthreads();

        float* heat = map ? heat1 : heat0;
        float* hb = heat + (size_t)b * GHW + (size_t)x0 * GW;
        for (int c4 = tid * 4; c4 < SH * GW; c4 += 4 * THR) {
            int4 iv = *reinterpret_cast<const int4*>(&strip[c4]);
            float4 fv;
            fv.x = __int_as_float(iv.x);
            fv.y = __int_as_float(iv.y);
            fv.z = __int_as_float(iv.z);
            fv.w = __int_as_float(iv.w);
            *reinterpret_cast<float4*>(hb + c4) = fv;
        }
    }
    if (phase_lo <= 2 && phase_hi >= 3 && do_bar)
        gbar(slots, nblk, blk, tid, MAGIC3, false, false);
    if (phase_hi < 3) return;

    // ---- Phase 3: fused gather ----
    const int row_len = 2 * N + 2 * M;
    if (vec_ok) {
        // 4096-pt chunks; task%B == blk%B (nblk%B==0) keeps b-affinity.
        const int nchunk = row_len >> 12;
        const int ntask = B * nchunk;
        for (int task = blk; task < ntask; task += nblk) {
            int b2 = task % B;
            int ch = task / B;
            int r0 = ch << 12;
            const float* hb = (r0 < N || (r0 >= N + M && r0 < 2 * N + M))
                              ? ((r0 < N) ? heat0 : heat1) : ((r0 < N + M) ? heat0 : heat1);
            const float* T = nullptr;
            const float* segbase;
            int stride, segoff;
            if (r0 < N)              { segbase = pc0    + (size_t)b2 * N * 3; stride = 3; segoff = r0;               T = &Tsh[b2][0]; hb = heat0; }
            else if (r0 < N + M)     { segbase = radar0 + (size_t)b2 * M * 6; stride = 6; segoff = r0 - N;           T = &Tsh[b2][0]; hb = heat0; }
            else if (r0 < 2 * N + M) { segbase = pc1    + (size_t)b2 * N * 3; stride = 3; segoff = r0 - N - M;       hb = heat1; }
            else                     { segbase = radar1 + (size_t)b2 * M * 6; stride = 6; segoff = r0 - 2 * N - M;   hb = heat1; }
            const float* hbb = hb + (size_t)b2 * GHW;

            const int pl = segoff + tid * 4;   // 4 consecutive points
            float X[4], Y[4], Z[4];
            if (stride == 3) {
                const f32x4* s = reinterpret_cast<const f32x4*>(segbase + (size_t)pl * 3);
                f32x4 f0 = __builtin_nontemporal_load(s + 0);
                f32x4 f1 = __builtin_nontemporal_load(s + 1);
                f32x4 f2 = __builtin_nontemporal_load(s + 2);
                X[0] = f0.x; Y[0] = f0.y; Z[0] = f0.z;
                X[1] = f0.w; Y[1] = f1.x; Z[1] = f1.y;
                X[2] = f1.z; Y[2] = f1.w; Z[2] = f2.x;
                X[3] = f2.y; Y[3] = f2.z; Z[3] = f2.w;
            } else {
                const f32x4* s = reinterpret_cast<const f32x4*>(segbase + (size_t)pl * 6);
                f32x4 g0 = __builtin_nontemporal_load(s + 0);
                f32x4 g1 = __builtin_nontemporal_load(s + 1);
                f32x4 g2 = __builtin_nontemporal_load(s + 2);
                f32x4 g3 = __builtin_nontemporal_load(s + 3);
                f32x4 g4 = __builtin_nontemporal_load(s + 4);
                f32x4 g5 = __builtin_nontemporal_load(s + 5);
                X[0] = g0.x; Y[0] = g0.y; Z[0] = g0.z;
                X[1] = g1.z; Y[1] = g1.w; Z[1] = g2.x;
                X[2] = g3.x; Y[2] = g3.y; Z[2] = g3.z;
                X[3] = g4.z; Y[3] = g4.w; Z[3] = g5.x;
            }

            float v[4];
            #pragma unroll
            for (int k = 0; k < 4; k++) {
                float px, py; int ix, iy; bool valid;
                voxelize_xyz(X[k], Y[k], Z[k], T, px, py, ix, iy, valid);
                v[k] = 0.0f;
                if (valid) v[k] = hbb[ix * GW + iy];
            }
            f32x4 res;
            res.x = v[0]; res.y = v[1]; res.z = v[2]; res.w = v[3];
            __builtin_nontemporal_store(res,
                reinterpret_cast<f32x4*>(out + (size_t)b2 * row_len + r0 + tid * 4));
        }
    } else {
        // scalar fallback (general shapes)
        long long tot = (long long)B * row_len;
        for (long long r = (long long)blk * THR + tid; r < tot;
             r += (long long)nblk * THR) {
            int b2 = (int)(r / row_len);
            int rl = (int)(r - (long long)b2 * row_len);
            const float* p;
            const float* T = nullptr;
            const float* hb;
            if (rl < N)              { p = pc0    + ((size_t)b2 * N + rl) * 3;             T = &Tsh[b2][0]; hb = heat0; }
            else if (rl < N + M)     { p = radar0 + ((size_t)b2 * M + (rl - N)) * 6;       T = &Tsh[b2][0]; hb = heat0; }
            else if (rl < 2 * N + M) { p = pc1    + ((size_t)b2 * N + (rl - N - M)) * 3;   hb = heat1; }
            else                     { p = radar1 + ((size_t)b2 * M + (rl - 2 * N - M)) * 6; hb = heat1; }
            float px, py; int ix, iy; bool valid;
            voxelize_xyz(p[0], p[1], p[2], T, px, py, ix, iy, valid);
            float v = 0.0f;
            if (valid) v = hb[(size_t)b2 * GHW + ix * GW + iy];
            __builtin_nontemporal_store(v, out + r);
        }
    }
}

extern "C" void kernel_launch(void* const* d_in, const int* in_sizes, int n_in,
                              void* d_out, int out_size, void* d_ws, size_t ws_size,
                              hipStream_t stream) {
    const float* pc0      = (const float*)d_in[0];
    const float* pc1      = (const float*)d_in[1];
    const float* radar0   = (const float*)d_in[2];
    const float* radar1   = (const float*)d_in[3];
    const float* pose0    = (const float*)d_in[4];
    const float* pose1    = (const float*)d_in[5];
    float* out = (float*)d_out;

    int B = in_sizes[4] / 16;
    int N = in_sizes[0] / (B * 3);
    int M = in_sizes[2] / (B * 6);

    int nblk = 2 * B * NSTRIP;   // 256 for B=8
    int vec_ok = ((N & 4095) == 0) && ((M & 4095) == 0);

    // workspace: heat0, heat1, entries, counts, slots
    float* heat0 = (float*)d_ws;
    float* heat1 = heat0 + (size_t)B * GHW;
    float2* entries = (float2*)(heat1 + (size_t)B * GHW);
    int* counts = (int*)(entries + (size_t)nblk * CAP);
    int* slots = counts + nblk;

    if (nblk <= 256) {
        // all blocks resident (<=1 per CU at 1024 thr, 76KB LDS): software
        // barrier is deadlock-free => single dispatch.
        mega_kernel<<<nblk, THR, 0, stream>>>(
            pc0, pc1, radar0, radar1, pose0, pose1, heat0, heat1,
            entries, counts, slots, out, B, N, M, 0, 3, 1, vec_ok);
    } else {
        // fallback: phases as separate dispatches (barriers off)
        for (int ph = 0; ph < 4; ph++)
            mega_kernel<<<nblk, THR, 0, stream>>>(
                pc0, pc1, radar0, radar1, pose0, pose1, heat0, heat1,
                entries, counts, slots, out, B, N, M, ph, ph, 0, vec_ok);
    }
}

// Round 10
// 158.127 us; speedup vs baseline: 4.5094x; 4.5094x over previous
//
#include <hip/hip_runtime.h>
#include <math.h>

// Grid constants from the reference
#define GH 512
#define GW 512
#define GHW (GH * GW)
#define RR 3
#define SH 32            // strip height (R6-proven; SH=16 doubles scan cost - R8 regression)
#define SSHIFT 5
#define NSTRIP (GH / SH) // 16
#define SCAP 1024        // per-strip staged capacity (mean ~580 @ SH=32, max ~700)
#define THR 1024         // heat threads (16 waves, 1 block/CU at 72KB LDS)
#define GTHR 256         // gather threads per block
#define GPT 8            // gather points per thread

typedef float f32x4 __attribute__((ext_vector_type(4)));  // nontemporal builtins
// reject HIP_vector_type (R7 compile fail) - use clang ext_vector_type.

// Precision model (validated, absmax 3.9e-3): pure f32 chain, *10.0f voxel
// scale, f32 expf, f32 pose (bit-identical to f64 for identity-rotation
// poses; validated R8). Heat max is order-free (int-bit atomicMax on
// positive floats) => strip/staging order cannot perturb results.
//
// Cost model (fitted R0-R9): T = 21 fixed + 41 ws-fill + Sum(device) + 13/dispatch.
// SETTLED: 2 dispatches is optimal. Coop launch +35us (R2,R4). Software
// barrier +500us (R9: relaxed atomic POLL is served by non-coherent local
// XCD L2; release-store only visible on eviction. RMW forces coherence,
// plain atomic loads don't - do not retry). Heat scan cost tracks strip
// redundancy: SH16=45/35us (R3/R8), SH32=26us (R6) => SH=32. Gather stuck
// ~28us at any occupancy/vectorization => per-thread latency on the random
// heat read; R10 widens to 8 pts/thread (8 heat loads in flight).

__device__ __forceinline__ void compute_pose(const float* __restrict__ P0,
                                             const float* __restrict__ P1,
                                             float* __restrict__ T) {
    float a00 = P1[0], a01 = P1[1], a02 = P1[2],  t1x = P1[3];
    float a10 = P1[4], a11 = P1[5], a12 = P1[6],  t1y = P1[7];
    float a20 = P1[8], a21 = P1[9], a22 = P1[10], t1z = P1[11];
    float c00 = a11 * a22 - a12 * a21;
    float c01 = a12 * a20 - a10 * a22;
    float c02 = a10 * a21 - a11 * a20;
    float det = a00 * c00 + a01 * c01 + a02 * c02;
    float id = 1.0f / det;
    float r00 = c00 * id;
    float r01 = (a02 * a21 - a01 * a22) * id;
    float r02 = (a01 * a12 - a02 * a11) * id;
    float r10 = c01 * id;
    float r11 = (a00 * a22 - a02 * a20) * id;
    float r12 = (a02 * a10 - a00 * a12) * id;
    float r20 = c02 * id;
    float r21 = (a01 * a20 - a00 * a21) * id;
    float r22 = (a00 * a11 - a01 * a10) * id;

    float b00 = P0[0], b01 = P0[1], b02 = P0[2],  t0x = P0[3];
    float b10 = P0[4], b11 = P0[5], b12 = P0[6],  t0y = P0[7];
    float b20 = P0[8], b21 = P0[9], b22 = P0[10], t0z = P0[11];
    float dx = t0x - t1x, dy = t0y - t1y, dz = t0z - t1z;

    T[0]  = r00 * b00 + r01 * b10 + r02 * b20;
    T[1]  = r00 * b01 + r01 * b11 + r02 * b21;
    T[2]  = r00 * b02 + r01 * b12 + r02 * b22;
    T[3]  = r00 * dx + r01 * dy + r02 * dz;
    T[4]  = r10 * b00 + r11 * b10 + r12 * b20;
    T[5]  = r10 * b01 + r11 * b11 + r12 * b21;
    T[6]  = r10 * b02 + r11 * b12 + r12 * b22;
    T[7]  = r10 * dx + r11 * dy + r12 * dz;
    T[8]  = r20 * b00 + r21 * b10 + r22 * b20;
    T[9]  = r20 * b01 + r21 * b11 + r22 * b21;
    T[10] = r20 * b02 + r21 * b12 + r22 * b22;
    T[11] = r20 * dx + r21 * dy + r22 * dz;
}

__device__ __forceinline__ void voxelize_xyz(float x, float y, float z,
                                             const float* __restrict__ T, // or nullptr
                                             float& px, float& py,
                                             int& ix, int& iy, bool& valid) {
    if (T) {
        float nx = T[0] * x + T[1] * y + T[2] * z + T[3];
        float ny = T[4] * x + T[5] * y + T[6] * z + T[7];
        float nz = T[8] * x + T[9] * y + T[10] * z + T[11];
        x = nx; y = ny; z = nz;
    }
    px = (x - 0.0f) * 10.0f;
    py = (y - (-25.6f)) * 10.0f;
    ix = (int)floorf(px);
    iy = (int)floorf(py);
    valid = (ix >= 0) & (ix < GH) & (iy >= 0) & (iy < GW) &
            (z >= -3.0f) & (z < 3.0f);
}

// One block per (strip, map, b), 1024 threads, 1 block/CU (72KB LDS).
// Phase A: scan the (map,b) radar slice as 4 pts/thread (6x16B coalesced
// loads), early-x reject, wave-aggregated LDS staging. Phase B: splat n*49
// (point,cell) pairs into the 32x512 LDS strip with atomicMax. Phase C:
// float4 writeback.
__global__ __launch_bounds__(THR)
void heat_strip_kernel(const float* __restrict__ radar0,
                       const float* __restrict__ radar1,
                       const float* __restrict__ pose0,
                       const float* __restrict__ pose1,
                       float* __restrict__ heat0,
                       float* __restrict__ heat1,
                       int B, int M) {
    __shared__ int strip[SH * GW];   // 64 KB
    __shared__ float2 sp[SCAP];      // 8 KB
    __shared__ float Tsh[8][12];
    __shared__ int sn;

    const int tid = threadIdx.x;
    const int lane = tid & 63;
    const int blk = blockIdx.x;
    const int b = blk % B;                 // == XCD id for B=8
    const int map = (blk / B) & 1;
    const int sx = blk / (2 * B);
    const int x0 = sx << SSHIFT;

    if (tid < B) compute_pose(pose0 + tid * 16, pose1 + tid * 16, &Tsh[tid][0]);
    if (tid == 0) sn = 0;
    {
        const int4 z4 = make_int4(0, 0, 0, 0);
        for (int c4 = tid * 4; c4 < SH * GW; c4 += 4 * THR)
            *reinterpret_cast<int4*>(&strip[c4]) = z4;
    }
    __syncthreads();

    const float* radar = map ? radar1 : radar0;
    const float* pb = radar + (size_t)b * M * 6;
    const f32x4* pb4 = reinterpret_cast<const f32x4*>(pb);
    const bool hasT = (map == 0);
    const float* T = &Tsh[b][0];

    // ---- Phase A: vectorized scan + wave-aggregated staging ----
    const int ng = M >> 2;                 // 4-point groups
    for (int g0 = 0; g0 < ng; g0 += THR) { // uniform bound: ballot reachable
        int g = g0 + tid;
        bool inr = (g < ng);
        float X[4], Y[4], Z[4];
        if (inr) {
            const f32x4* s = pb4 + (size_t)g * 6;
            f32x4 q0 = s[0], q1 = s[1], q2 = s[2];
            f32x4 q3 = s[3], q4 = s[4], q5 = s[5];
            X[0] = q0.x; Y[0] = q0.y; Z[0] = q0.z;
            X[1] = q1.z; Y[1] = q1.w; Z[1] = q2.x;
            X[2] = q3.x; Y[2] = q3.y; Z[2] = q3.z;
            X[3] = q4.z; Y[3] = q4.w; Z[3] = q5.x;
        }
        #pragma unroll
        for (int j = 0; j < 4; j++) {
            bool valid = false;
            float px = 0.0f, py = 0.0f;
            if (inr) {
                float x = X[j], y = Y[j], z = Z[j];
                float nx = hasT ? (T[0] * x + T[1] * y + T[2] * z + T[3]) : x;
                px = (nx - 0.0f) * 10.0f;
                int ix = (int)floorf(px);
                if (ix >= x0 - RR && ix <= x0 + SH - 1 + RR) {
                    float ny = hasT ? (T[4] * x + T[5] * y + T[6] * z + T[7]) : y;
                    float nz = hasT ? (T[8] * x + T[9] * y + T[10] * z + T[11]) : z;
                    py = (ny - (-25.6f)) * 10.0f;
                    int iy = (int)floorf(py);
                    valid = (ix >= 0) & (ix < GH) & (iy >= 0) & (iy < GW) &
                            (nz >= -3.0f) & (nz < 3.0f);
                }
            }
            unsigned long long mask = __ballot(valid);
            if (valid) {
                int leader = __ffsll((long long)mask) - 1;
                int cnt = __popcll(mask);
                int wbase = 0;
                if (lane == leader) wbase = atomicAdd(&sn, cnt);
                wbase = __shfl(wbase, leader);
                int off = __popcll(mask & ((1ull << lane) - 1ull));
                int slot = wbase + off;
                if (slot < SCAP) sp[slot] = make_float2(px, py);
            }
        }
    }
    if (M & 3) {   // scalar remainder (uniform reach)
        int i = (M & ~3) + tid;
        bool valid = false;
        float px = 0.0f, py = 0.0f;
        if (i < M) {
            const float* p = pb + (size_t)i * 6;
            float x = p[0], y = p[1], z = p[2];
            float nx = hasT ? (T[0] * x + T[1] * y + T[2] * z + T[3]) : x;
            px = (nx - 0.0f) * 10.0f;
            int ix = (int)floorf(px);
            if (ix >= x0 - RR && ix <= x0 + SH - 1 + RR) {
                float ny = hasT ? (T[4] * x + T[5] * y + T[6] * z + T[7]) : y;
                float nz = hasT ? (T[8] * x + T[9] * y + T[10] * z + T[11]) : z;
                py = (ny - (-25.6f)) * 10.0f;
                int iy = (int)floorf(py);
                valid = (ix >= 0) & (ix < GH) & (iy >= 0) & (iy < GW) &
                        (nz >= -3.0f) & (nz < 3.0f);
            }
        }
        unsigned long long mask = __ballot(valid);
        if (valid) {
            int leader = __ffsll((long long)mask) - 1;
            int cnt = __popcll(mask);
            int wbase = 0;
            if (lane == leader) wbase = atomicAdd(&sn, cnt);
            wbase = __shfl(wbase, leader);
            int off = __popcll(mask & ((1ull << lane) - 1ull));
            int slot = wbase + off;
            if (slot < SCAP) sp[slot] = make_float2(px, py);
        }
    }
    __syncthreads();

    // ---- Phase B: splat ----
    int n = sn; if (n > SCAP) n = SCAP;
    const int total = n * 49;
    for (int t = tid; t < total; t += THR) {
        int pi = t / 49;
        int c = t - pi * 49;
        float px = sp[pi].x;
        float py = sp[pi].y;
        int ix = (int)floorf(px);
        int iy = (int)floorf(py);
        int dx = c / 7 - RR;
        int dy = c - (c / 7) * 7 - RR;
        int gx = ix + dx, gy = iy + dy;
        if (gx < x0 || gx >= x0 + SH || gy < 0 || gy >= GW) continue;
        float ddx = ((float)gx + 0.5f) - px;
        float ddy = ((float)gy + 0.5f) - py;
        float d2 = ddx * ddx + ddy * ddy;
        float val = expf(-d2 / 4.5f);
        atomicMax(&strip[(gx - x0) * GW + gy], __float_as_int(val));
    }
    __syncthreads();

    // ---- Phase C: writeback ----
    float* heat = map ? heat1 : heat0;
    float* hb = heat + (size_t)b * GHW + (size_t)x0 * GW;
    for (int c4 = tid * 4; c4 < SH * GW; c4 += 4 * THR) {
        int4 iv = *reinterpret_cast<const int4*>(&strip[c4]);
        float4 fv;
        fv.x = __int_as_float(iv.x);
        fv.y = __int_as_float(iv.y);
        fv.z = __int_as_float(iv.z);
        fv.w = __int_as_float(iv.w);
        *reinterpret_cast<float4*>(hb + c4) = fv;
    }
}

// Vectorized fused gather (requires N%2048==0 && M%2048==0, true here:
// N=262144, M=8192). One block per (b, 2048-pt chunk), chunk uniform in
// segment. Each thread owns 8 CONSECUTIVE points (pc: 6x16B, radar: 12x16B
// loads; out: 2x16B stores) => 8 independent random heat reads in flight
// per thread (R10: gather stuck ~28us at any occupancy => per-thread
// latency on the scattered heat read; widen MLP). blockIdx.x == b ==
// linear%8 keeps heat XCD-L2-local; nt on streamed data keeps L2 for heat.
__global__ __launch_bounds__(GTHR)
void gather_vec_kernel(const float* __restrict__ pc0,
                       const float* __restrict__ pc1,
                       const float* __restrict__ radar0,
                       const float* __restrict__ radar1,
                       const float* __restrict__ pose0,
                       const float* __restrict__ pose1,
                       const float* __restrict__ heat0,
                       const float* __restrict__ heat1,
                       float* __restrict__ out,
                       int N, int M) {
    __shared__ float Tsh[12];
    const int row_len = 2 * N + 2 * M;
    const int b = blockIdx.x;

    if (threadIdx.x == 0) compute_pose(pose0 + b * 16, pose1 + b * 16, Tsh);
    __syncthreads();

    const float* hb0 = heat0 + (size_t)b * GHW;
    const float* hb1 = heat1 + (size_t)b * GHW;

    const int CH = GTHR * GPT;        // 2048 points per chunk
    const int ncp = N / CH;
    const int ncr = M / CH;
    const int c = blockIdx.y;

    const float* segbase;
    const float* T = nullptr;
    const float* hb;
    int stride, out_base, pseg;
    if (c < ncp) {
        segbase = pc0 + (size_t)b * N * 3; stride = 3;
        out_base = 0;          T = Tsh; hb = hb0; pseg = c * CH;
    } else if (c < ncp + ncr) {
        segbase = radar0 + (size_t)b * M * 6; stride = 6;
        out_base = N;          T = Tsh; hb = hb0; pseg = (c - ncp) * CH;
    } else if (c < 2 * ncp + ncr) {
        segbase = pc1 + (size_t)b * N * 3; stride = 3;
        out_base = N + M;               hb = hb1; pseg = (c - ncp - ncr) * CH;
    } else {
        segbase = radar1 + (size_t)b * M * 6; stride = 6;
        out_base = 2 * N + M;           hb = hb1; pseg = (c - 2 * ncp - ncr) * CH;
    }

    const int p0 = pseg + threadIdx.x * GPT;   // 8 consecutive points
    float X[8], Y[8], Z[8];
    if (stride == 3) {
        const f32x4* s = reinterpret_cast<const f32x4*>(segbase + (size_t)p0 * 3);
        #pragma unroll
        for (int h = 0; h < 2; h++) {          // 2 groups of 4 pts / 3 regs
            f32x4 f0 = __builtin_nontemporal_load(s + 3 * h + 0);
            f32x4 f1 = __builtin_nontemporal_load(s + 3 * h + 1);
            f32x4 f2 = __builtin_nontemporal_load(s + 3 * h + 2);
            X[4*h+0] = f0.x; Y[4*h+0] = f0.y; Z[4*h+0] = f0.z;
            X[4*h+1] = f0.w; Y[4*h+1] = f1.x; Z[4*h+1] = f1.y;
            X[4*h+2] = f1.z; Y[4*h+2] = f1.w; Z[4*h+2] = f2.x;
            X[4*h+3] = f2.y; Y[4*h+3] = f2.z; Z[4*h+3] = f2.w;
        }
    } else {
        const f32x4* s = reinterpret_cast<const f32x4*>(segbase + (size_t)p0 * 6);
        #pragma unroll
        for (int h = 0; h < 2; h++) {          // 2 groups of 4 pts / 6 regs
            f32x4 g0 = __builtin_nontemporal_load(s + 6 * h + 0);
            f32x4 g1 = __builtin_nontemporal_load(s + 6 * h + 1);
            f32x4 g2 = __builtin_nontemporal_load(s + 6 * h + 2);
            f32x4 g3 = __builtin_nontemporal_load(s + 6 * h + 3);
            f32x4 g4 = __builtin_nontemporal_load(s + 6 * h + 4);
            f32x4 g5 = __builtin_nontemporal_load(s + 6 * h + 5);
            X[4*h+0] = g0.x; Y[4*h+0] = g0.y; Z[4*h+0] = g0.z;
            X[4*h+1] = g1.z; Y[4*h+1] = g1.w; Z[4*h+1] = g2.x;
            X[4*h+2] = g3.x; Y[4*h+2] = g3.y; Z[4*h+2] = g3.z;
            X[4*h+3] = g4.z; Y[4*h+3] = g4.w; Z[4*h+3] = g5.x;
        }
    }

    float v[8];
    #pragma unroll
    for (int k = 0; k < 8; k++) {
        float px, py; int ix, iy; bool valid;
        voxelize_xyz(X[k], Y[k], Z[k], T, px, py, ix, iy, valid);
        v[k] = 0.0f;
        if (valid) v[k] = hb[ix * GW + iy];
    }

    float* ob = out + (size_t)b * row_len + out_base + p0;
    f32x4 r0; r0.x = v[0]; r0.y = v[1]; r0.z = v[2]; r0.w = v[3];
    f32x4 r1; r1.x = v[4]; r1.y = v[5]; r1.z = v[6]; r1.w = v[7];
    __builtin_nontemporal_store(r0, reinterpret_cast<f32x4*>(ob));
    __builtin_nontemporal_store(r1, reinterpret_cast<f32x4*>(ob + 4));
}

// Scalar fallback gather (general N, M).
__global__ __launch_bounds__(GTHR)
void gather_fused_kernel(const float* __restrict__ pc0,
                         const float* __restrict__ pc1,
                         const float* __restrict__ radar0,
                         const float* __restrict__ radar1,
                         const float* __restrict__ pose0,
                         const float* __restrict__ pose1,
                         const float* __restrict__ heat0,
                         const float* __restrict__ heat1,
                         float* __restrict__ out,
                         int N, int M) {
    __shared__ float Tsh[12];
    const int row_len = 2 * N + 2 * M;
    const int b = blockIdx.x;
    const int base = blockIdx.y * 1024 + threadIdx.x;

    if (threadIdx.x == 0) compute_pose(pose0 + b * 16, pose1 + b * 16, Tsh);
    __syncthreads();

    const float* hb0 = heat0 + (size_t)b * GHW;
    const float* hb1 = heat1 + (size_t)b * GHW;

    #pragma unroll
    for (int k = 0; k < 4; k++) {
        int r = base + k * GTHR;
        if (r >= row_len) continue;
        const float* p;
        const float* T = nullptr;
        const float* hb;
        if (r < N) {
            p = pc0 + ((size_t)b * N + r) * 3; T = Tsh; hb = hb0;
        } else if (r < N + M) {
            p = radar0 + ((size_t)b * M + (r - N)) * 6; T = Tsh; hb = hb0;
        } else if (r < 2 * N + M) {
            p = pc1 + ((size_t)b * N + (r - N - M)) * 3; hb = hb1;
        } else {
            p = radar1 + ((size_t)b * M + (r - 2 * N - M)) * 6; hb = hb1;
        }
        float px, py; int ix, iy; bool valid;
        voxelize_xyz(p[0], p[1], p[2], T, px, py, ix, iy, valid);
        float v = 0.0f;
        if (valid) v = hb[ix * GW + iy];
        __builtin_nontemporal_store(v, out + (size_t)b * row_len + r);
    }
}

extern "C" void kernel_launch(void* const* d_in, const int* in_sizes, int n_in,
                              void* d_out, int out_size, void* d_ws, size_t ws_size,
                              hipStream_t stream) {
    const float* pc0      = (const float*)d_in[0];
    const float* pc1      = (const float*)d_in[1];
    const float* radar0   = (const float*)d_in[2];
    const float* radar1   = (const float*)d_in[3];
    const float* pose0    = (const float*)d_in[4];
    const float* pose1    = (const float*)d_in[5];
    float* out = (float*)d_out;

    int B = in_sizes[4] / 16;
    int N = in_sizes[0] / (B * 3);
    int M = in_sizes[2] / (B * 6);
    int row_len = 2 * N + 2 * M;

    // workspace layout: just the two heatmaps
    float* heat0 = (float*)d_ws;
    float* heat1 = heat0 + (size_t)B * GHW;

    int nblk = 2 * B * NSTRIP;   // 256 for B=8: 1 block/CU
    heat_strip_kernel<<<nblk, THR, 0, stream>>>(
        radar0, radar1, pose0, pose1, heat0, heat1, B, M);

    const int CH = GTHR * GPT;   // 2048
    if ((N % CH) == 0 && (M % CH) == 0) {
        dim3 ggrid(B, 2 * (N / CH) + 2 * (M / CH));
        gather_vec_kernel<<<ggrid, GTHR, 0, stream>>>(
            pc0, pc1, radar0, radar1, pose0, pose1, heat0, heat1, out, N, M);
    } else {
        dim3 ggrid(B, (row_len + 1023) / 1024);
        gather_fused_kernel<<<ggrid, GTHR, 0, stream>>>(
            pc0, pc1, radar0, radar1, pose0, pose1, heat0, heat1, out, N, M);
    }
}

// Round 11
// 140.005 us; speedup vs baseline: 5.0930x; 1.1294x over previous
//
#include <hip/hip_runtime.h>
#include <math.h>

// Grid constants from the reference
#define GH 512
#define GW 512
#define GHW (GH * GW)
#define RR 3
#define SH 32            // strip height (R6/R10-proven; SH=16 doubles scan cost)
#define SSHIFT 5
#define NSTRIP (GH / SH) // 16
#define SCAP 1024        // per-strip staged capacity (mean ~580 @ SH=32)
#define THR 1024         // heat threads (16 waves, 1 block/CU at 72KB LDS)
#define GTHR 256         // gather threads per block
#define GCH 1024         // gather points per chunk/block

typedef float f32x4 __attribute__((ext_vector_type(4)));  // nontemporal builtins
// reject HIP_vector_type (R7 compile fail) - use clang ext_vector_type.

// Precision model (validated, absmax 3.9e-3): pure f32 chain, *10.0f voxel
// scale, f32 expf, f32 pose (bit-identical to f64 for identity-rotation
// poses; validated R8). Heat max is order-free (int-bit atomicMax on
// positive floats) => strip/staging order cannot perturb results.
//
// Cost model (fitted R0-R10): T = 21 fixed + 41 ws-fill + Sum(device) + 13/dispatch.
// SETTLED: 2 dispatches (coop +35us R2/R4; software barrier +500us R9 -
// relaxed atomic polls served by non-coherent local XCD L2). Heat: R10 form
// = 19.6us, keep. Gather ledger: scalar strided = 28us (2.6 TB/s,
// transaction-bound); consecutive-pts-per-thread vec = 50us (R10: 96B lane
// stride -> 64 lines/instr; split 32B stores -> nt RMW, WRITE 2x). R11:
// LDS-staged chunk loads (lane-contiguous f32x4 = perfect coalescing) +
// strided per-thread compute + lane-contiguous scalar nt stores (full-line
// coverage per instr - no RMW, L2 bypass keeps heat resident).

__device__ __forceinline__ void compute_pose(const float* __restrict__ P0,
                                             const float* __restrict__ P1,
                                             float* __restrict__ T) {
    float a00 = P1[0], a01 = P1[1], a02 = P1[2],  t1x = P1[3];
    float a10 = P1[4], a11 = P1[5], a12 = P1[6],  t1y = P1[7];
    float a20 = P1[8], a21 = P1[9], a22 = P1[10], t1z = P1[11];
    float c00 = a11 * a22 - a12 * a21;
    float c01 = a12 * a20 - a10 * a22;
    float c02 = a10 * a21 - a11 * a20;
    float det = a00 * c00 + a01 * c01 + a02 * c02;
    float id = 1.0f / det;
    float r00 = c00 * id;
    float r01 = (a02 * a21 - a01 * a22) * id;
    float r02 = (a01 * a12 - a02 * a11) * id;
    float r10 = c01 * id;
    float r11 = (a00 * a22 - a02 * a20) * id;
    float r12 = (a02 * a10 - a00 * a12) * id;
    float r20 = c02 * id;
    float r21 = (a01 * a20 - a00 * a21) * id;
    float r22 = (a00 * a11 - a01 * a10) * id;

    float b00 = P0[0], b01 = P0[1], b02 = P0[2],  t0x = P0[3];
    float b10 = P0[4], b11 = P0[5], b12 = P0[6],  t0y = P0[7];
    float b20 = P0[8], b21 = P0[9], b22 = P0[10], t0z = P0[11];
    float dx = t0x - t1x, dy = t0y - t1y, dz = t0z - t1z;

    T[0]  = r00 * b00 + r01 * b10 + r02 * b20;
    T[1]  = r00 * b01 + r01 * b11 + r02 * b21;
    T[2]  = r00 * b02 + r01 * b12 + r02 * b22;
    T[3]  = r00 * dx + r01 * dy + r02 * dz;
    T[4]  = r10 * b00 + r11 * b10 + r12 * b20;
    T[5]  = r10 * b01 + r11 * b11 + r12 * b21;
    T[6]  = r10 * b02 + r11 * b12 + r12 * b22;
    T[7]  = r10 * dx + r11 * dy + r12 * dz;
    T[8]  = r20 * b00 + r21 * b10 + r22 * b20;
    T[9]  = r20 * b01 + r21 * b11 + r22 * b21;
    T[10] = r20 * b02 + r21 * b12 + r22 * b22;
    T[11] = r20 * dx + r21 * dy + r22 * dz;
}

__device__ __forceinline__ void voxelize_xyz(float x, float y, float z,
                                             const float* __restrict__ T, // or nullptr
                                             float& px, float& py,
                                             int& ix, int& iy, bool& valid) {
    if (T) {
        float nx = T[0] * x + T[1] * y + T[2] * z + T[3];
        float ny = T[4] * x + T[5] * y + T[6] * z + T[7];
        float nz = T[8] * x + T[9] * y + T[10] * z + T[11];
        x = nx; y = ny; z = nz;
    }
    px = (x - 0.0f) * 10.0f;
    py = (y - (-25.6f)) * 10.0f;
    ix = (int)floorf(px);
    iy = (int)floorf(py);
    valid = (ix >= 0) & (ix < GH) & (iy >= 0) & (iy < GW) &
            (z >= -3.0f) & (z < 3.0f);
}

// Heat kernel: UNCHANGED from R10 (measured 19.6us). One block per
// (strip, map, b), 1024 threads, 1 block/CU (72KB LDS). Phase A: vec scan
// (4 pts/thread) + early-x reject + wave-aggregated staging; Phase B: n*49
// LDS atomicMax splat; Phase C: float4 writeback.
__global__ __launch_bounds__(THR)
void heat_strip_kernel(const float* __restrict__ radar0,
                       const float* __restrict__ radar1,
                       const float* __restrict__ pose0,
                       const float* __restrict__ pose1,
                       float* __restrict__ heat0,
                       float* __restrict__ heat1,
                       int B, int M) {
    __shared__ int strip[SH * GW];   // 64 KB
    __shared__ float2 sp[SCAP];      // 8 KB
    __shared__ float Tsh[8][12];
    __shared__ int sn;

    const int tid = threadIdx.x;
    const int lane = tid & 63;
    const int blk = blockIdx.x;
    const int b = blk % B;                 // == XCD id for B=8
    const int map = (blk / B) & 1;
    const int sx = blk / (2 * B);
    const int x0 = sx << SSHIFT;

    if (tid < B) compute_pose(pose0 + tid * 16, pose1 + tid * 16, &Tsh[tid][0]);
    if (tid == 0) sn = 0;
    {
        const int4 z4 = make_int4(0, 0, 0, 0);
        for (int c4 = tid * 4; c4 < SH * GW; c4 += 4 * THR)
            *reinterpret_cast<int4*>(&strip[c4]) = z4;
    }
    __syncthreads();

    const float* radar = map ? radar1 : radar0;
    const float* pb = radar + (size_t)b * M * 6;
    const f32x4* pb4 = reinterpret_cast<const f32x4*>(pb);
    const bool hasT = (map == 0);
    const float* T = &Tsh[b][0];

    const int ng = M >> 2;                 // 4-point groups
    for (int g0 = 0; g0 < ng; g0 += THR) { // uniform bound: ballot reachable
        int g = g0 + tid;
        bool inr = (g < ng);
        float X[4], Y[4], Z[4];
        if (inr) {
            const f32x4* s = pb4 + (size_t)g * 6;
            f32x4 q0 = s[0], q1 = s[1], q2 = s[2];
            f32x4 q3 = s[3], q4 = s[4], q5 = s[5];
            X[0] = q0.x; Y[0] = q0.y; Z[0] = q0.z;
            X[1] = q1.z; Y[1] = q1.w; Z[1] = q2.x;
            X[2] = q3.x; Y[2] = q3.y; Z[2] = q3.z;
            X[3] = q4.z; Y[3] = q4.w; Z[3] = q5.x;
        }
        #pragma unroll
        for (int j = 0; j < 4; j++) {
            bool valid = false;
            float px = 0.0f, py = 0.0f;
            if (inr) {
                float x = X[j], y = Y[j], z = Z[j];
                float nx = hasT ? (T[0] * x + T[1] * y + T[2] * z + T[3]) : x;
                px = (nx - 0.0f) * 10.0f;
                int ix = (int)floorf(px);
                if (ix >= x0 - RR && ix <= x0 + SH - 1 + RR) {
                    float ny = hasT ? (T[4] * x + T[5] * y + T[6] * z + T[7]) : y;
                    float nz = hasT ? (T[8] * x + T[9] * y + T[10] * z + T[11]) : z;
                    py = (ny - (-25.6f)) * 10.0f;
                    int iy = (int)floorf(py);
                    valid = (ix >= 0) & (ix < GH) & (iy >= 0) & (iy < GW) &
                            (nz >= -3.0f) & (nz < 3.0f);
                }
            }
            unsigned long long mask = __ballot(valid);
            if (valid) {
                int leader = __ffsll((long long)mask) - 1;
                int cnt = __popcll(mask);
                int wbase = 0;
                if (lane == leader) wbase = atomicAdd(&sn, cnt);
                wbase = __shfl(wbase, leader);
                int off = __popcll(mask & ((1ull << lane) - 1ull));
                int slot = wbase + off;
                if (slot < SCAP) sp[slot] = make_float2(px, py);
            }
        }
    }
    if (M & 3) {   // scalar remainder (uniform reach)
        int i = (M & ~3) + tid;
        bool valid = false;
        float px = 0.0f, py = 0.0f;
        if (i < M) {
            const float* p = pb + (size_t)i * 6;
            float x = p[0], y = p[1], z = p[2];
            float nx = hasT ? (T[0] * x + T[1] * y + T[2] * z + T[3]) : x;
            px = (nx - 0.0f) * 10.0f;
            int ix = (int)floorf(px);
            if (ix >= x0 - RR && ix <= x0 + SH - 1 + RR) {
                float ny = hasT ? (T[4] * x + T[5] * y + T[6] * z + T[7]) : y;
                float nz = hasT ? (T[8] * x + T[9] * y + T[10] * z + T[11]) : z;
                py = (ny - (-25.6f)) * 10.0f;
                int iy = (int)floorf(py);
                valid = (ix >= 0) & (ix < GH) & (iy >= 0) & (iy < GW) &
                        (nz >= -3.0f) & (nz < 3.0f);
            }
        }
        unsigned long long mask = __ballot(valid);
        if (valid) {
            int leader = __ffsll((long long)mask) - 1;
            int cnt = __popcll(mask);
            int wbase = 0;
            if (lane == leader) wbase = atomicAdd(&sn, cnt);
            wbase = __shfl(wbase, leader);
            int off = __popcll(mask & ((1ull << lane) - 1ull));
            int slot = wbase + off;
            if (slot < SCAP) sp[slot] = make_float2(px, py);
        }
    }
    __syncthreads();

    int n = sn; if (n > SCAP) n = SCAP;
    const int total = n * 49;
    for (int t = tid; t < total; t += THR) {
        int pi = t / 49;
        int c = t - pi * 49;
        float px = sp[pi].x;
        float py = sp[pi].y;
        int ix = (int)floorf(px);
        int iy = (int)floorf(py);
        int dx = c / 7 - RR;
        int dy = c - (c / 7) * 7 - RR;
        int gx = ix + dx, gy = iy + dy;
        if (gx < x0 || gx >= x0 + SH || gy < 0 || gy >= GW) continue;
        float ddx = ((float)gx + 0.5f) - px;
        float ddy = ((float)gy + 0.5f) - py;
        float d2 = ddx * ddx + ddy * ddy;
        float val = expf(-d2 / 4.5f);
        atomicMax(&strip[(gx - x0) * GW + gy], __float_as_int(val));
    }
    __syncthreads();

    float* heat = map ? heat1 : heat0;
    float* hb = heat + (size_t)b * GHW + (size_t)x0 * GW;
    for (int c4 = tid * 4; c4 < SH * GW; c4 += 4 * THR) {
        int4 iv = *reinterpret_cast<const int4*>(&strip[c4]);
        float4 fv;
        fv.x = __int_as_float(iv.x);
        fv.y = __int_as_float(iv.y);
        fv.z = __int_as_float(iv.z);
        fv.w = __int_as_float(iv.w);
        *reinterpret_cast<float4*>(hb + c4) = fv;
    }
}

// LDS-staged gather (requires N%1024==0 && M%1024==0; true here). One block
// per (b, 1024-pt chunk), chunk uniform in segment. Stage: lane-contiguous
// f32x4 nt loads (16B/lane consecutive = perfect per-instruction
// coalescing) -> LDS (12-24KB). Compute: each thread owns 4 points STRIDED
// by 256 (LDS reads: stride-3 conflict-free / stride-6 2-way-free). Store:
// lane-contiguous scalar nt (each instr fully covers its 64B lines - no
// RMW; L2 bypass keeps heat resident). blockIdx.x == b == linear%8 keeps
// heat XCD-L2-local.
__global__ __launch_bounds__(GTHR)
void gather_lds_kernel(const float* __restrict__ pc0,
                       const float* __restrict__ pc1,
                       const float* __restrict__ radar0,
                       const float* __restrict__ radar1,
                       const float* __restrict__ pose0,
                       const float* __restrict__ pose1,
                       const float* __restrict__ heat0,
                       const float* __restrict__ heat1,
                       float* __restrict__ out,
                       int N, int M) {
    __shared__ float stage[6 * GCH];   // 24 KB (radar); pc uses 12 KB
    __shared__ float Tsh[12];
    const int tid = threadIdx.x;
    const int row_len = 2 * N + 2 * M;
    const int b = blockIdx.x;

    if (tid == 0) compute_pose(pose0 + b * 16, pose1 + b * 16, Tsh);

    const int ncp = N / GCH;
    const int ncr = M / GCH;
    const int c = blockIdx.y;

    const float* segbase;
    const float* T = nullptr;
    const float* hb;
    int stride, out_base, pseg;
    if (c < ncp) {
        segbase = pc0 + (size_t)b * N * 3; stride = 3;
        out_base = 0;          T = Tsh; hb = heat0; pseg = c * GCH;
    } else if (c < ncp + ncr) {
        segbase = radar0 + (size_t)b * M * 6; stride = 6;
        out_base = N;          T = Tsh; hb = heat0; pseg = (c - ncp) * GCH;
    } else if (c < 2 * ncp + ncr) {
        segbase = pc1 + (size_t)b * N * 3; stride = 3;
        out_base = N + M;               hb = heat1; pseg = (c - ncp - ncr) * GCH;
    } else {
        segbase = radar1 + (size_t)b * M * 6; stride = 6;
        out_base = 2 * N + M;           hb = heat1; pseg = (c - 2 * ncp - ncr) * GCH;
    }
    const float* hbb = hb + (size_t)b * GHW;

    // ---- stage chunk: lane-contiguous f32x4 loads -> LDS ----
    {
        const f32x4* src = reinterpret_cast<const f32x4*>(
            segbase + (size_t)pseg * stride);
        f32x4* dst = reinterpret_cast<f32x4*>(stage);
        const int nv = (GCH * stride) >> 2;   // 768 (pc) or 1536 (radar)
        for (int i = tid; i < nv; i += GTHR)
            dst[i] = __builtin_nontemporal_load(src + i);
    }
    __syncthreads();

    // ---- compute + lane-contiguous scalar stores ----
    float* ob = out + (size_t)b * row_len + out_base + pseg;
    #pragma unroll
    for (int j = 0; j < GCH / GTHR; j++) {
        int k = j * GTHR + tid;            // point within chunk (strided)
        const float* p = stage + k * stride;
        float px, py; int ix, iy; bool valid;
        voxelize_xyz(p[0], p[1], p[2], T, px, py, ix, iy, valid);
        float v = 0.0f;
        if (valid) v = hbb[ix * GW + iy];
        __builtin_nontemporal_store(v, ob + k);
    }
}

// Scalar fallback gather (general N, M).
__global__ __launch_bounds__(GTHR)
void gather_fused_kernel(const float* __restrict__ pc0,
                         const float* __restrict__ pc1,
                         const float* __restrict__ radar0,
                         const float* __restrict__ radar1,
                         const float* __restrict__ pose0,
                         const float* __restrict__ pose1,
                         const float* __restrict__ heat0,
                         const float* __restrict__ heat1,
                         float* __restrict__ out,
                         int N, int M) {
    __shared__ float Tsh[12];
    const int row_len = 2 * N + 2 * M;
    const int b = blockIdx.x;
    const int base = blockIdx.y * 1024 + threadIdx.x;

    if (threadIdx.x == 0) compute_pose(pose0 + b * 16, pose1 + b * 16, Tsh);
    __syncthreads();

    const float* hb0 = heat0 + (size_t)b * GHW;
    const float* hb1 = heat1 + (size_t)b * GHW;

    #pragma unroll
    for (int k = 0; k < 4; k++) {
        int r = base + k * GTHR;
        if (r >= row_len) continue;
        const float* p;
        const float* T = nullptr;
        const float* hb;
        if (r < N) {
            p = pc0 + ((size_t)b * N + r) * 3; T = Tsh; hb = hb0;
        } else if (r < N + M) {
            p = radar0 + ((size_t)b * M + (r - N)) * 6; T = Tsh; hb = hb0;
        } else if (r < 2 * N + M) {
            p = pc1 + ((size_t)b * N + (r - N - M)) * 3; hb = hb1;
        } else {
            p = radar1 + ((size_t)b * M + (r - 2 * N - M)) * 6; hb = hb1;
        }
        float px, py; int ix, iy; bool valid;
        voxelize_xyz(p[0], p[1], p[2], T, px, py, ix, iy, valid);
        float v = 0.0f;
        if (valid) v = hb[ix * GW + iy];
        __builtin_nontemporal_store(v, out + (size_t)b * row_len + r);
    }
}

extern "C" void kernel_launch(void* const* d_in, const int* in_sizes, int n_in,
                              void* d_out, int out_size, void* d_ws, size_t ws_size,
                              hipStream_t stream) {
    const float* pc0      = (const float*)d_in[0];
    const float* pc1      = (const float*)d_in[1];
    const float* radar0   = (const float*)d_in[2];
    const float* radar1   = (const float*)d_in[3];
    const float* pose0    = (const float*)d_in[4];
    const float* pose1    = (const float*)d_in[5];
    float* out = (float*)d_out;

    int B = in_sizes[4] / 16;
    int N = in_sizes[0] / (B * 3);
    int M = in_sizes[2] / (B * 6);
    int row_len = 2 * N + 2 * M;

    // workspace layout: just the two heatmaps
    float* heat0 = (float*)d_ws;
    float* heat1 = heat0 + (size_t)B * GHW;

    int nblk = 2 * B * NSTRIP;   // 256 for B=8: 1 block/CU
    heat_strip_kernel<<<nblk, THR, 0, stream>>>(
        radar0, radar1, pose0, pose1, heat0, heat1, B, M);

    if ((N % GCH) == 0 && (M % GCH) == 0) {
        dim3 ggrid(B, 2 * (N / GCH) + 2 * (M / GCH));
        gather_lds_kernel<<<ggrid, GTHR, 0, stream>>>(
            pc0, pc1, radar0, radar1, pose0, pose1, heat0, heat1, out, N, M);
    } else {
        dim3 ggrid(B, (row_len + 1023) / 1024);
        gather_fused_kernel<<<ggrid, GTHR, 0, stream>>>(
            pc0, pc1, radar0, radar1, pose0, pose1, heat0, heat1, out, N, M);
    }
}